// Round 13
// baseline (928.287 us; speedup 1.0000x reference)
//
#include <hip/hip_runtime.h>
#include <hip/hip_bf16.h>
#include <cstdint>
#include <math.h>

#define TOKENS 4096
#define DMODEL 4096
#define DFF    16384

typedef __attribute__((ext_vector_type(4)))  int i32x4;
typedef __attribute__((ext_vector_type(16))) int i32x16;
typedef __attribute__((address_space(1))) unsigned int glb_u32;
typedef __attribute__((address_space(3))) unsigned int lds_u32;

// ---------------- pack: int32 -> int8 (values already in [-127,127]) ----------------
__global__ void pack_i8_kernel(const int* __restrict__ src, unsigned* __restrict__ dst, long n4) {
    long i = (long)blockIdx.x * blockDim.x + threadIdx.x;
    const long stride = (long)gridDim.x * blockDim.x;
    for (; i < n4; i += stride) {
        const int4 v = ((const int4*)src)[i];
        unsigned p = (unsigned(v.x) & 255u) | ((unsigned(v.y) & 255u) << 8) |
                     ((unsigned(v.z) & 255u) << 16) | ((unsigned(v.w) & 255u) << 24);
        dst[i] = p;
    }
}

__global__ void zero_u32_kernel(unsigned* __restrict__ p, int n) {
    int i = blockIdx.x * blockDim.x + threadIdx.x;
    if (i < n) p[i] = 0u;
}

// ---------------- int8 GEMM, C[row][col] = sum_k A[row][k]*B[col][k] ----------------
// R13 = R12 (128x256 tile, BK=64, 512 thr / 8 waves 2Mx4N, wave tile 64x64,
// 3-buf 72KB LDS -> 2 independent blocks/CU, stage-ahead-2, counted vmcnt(3),
// unrolled x3 literal-buf loop, pointer-increment staging) with ONE change:
// MFMA shape 16x16x64 -> 32x32x32. Same bytes (8 b128 frag reads/wave/K-tile),
// same acc budget (2x2 frags x 16 = 64 regs), but 8 MFMA instead of 16 and
// half the ds_read->MFMA dependency edges (R12 showed neither LDS port (52%)
// nor MFMA (35%) saturated -> residual is per-phase dependency/issue count).
// 32x32x32 A/B frag: lane l holds row (l&31), 16 bytes at kslice*32+(l>>5)*16;
// swizzled chunk c = ((ks<<1)|l5) ^ ((row>>1)&3) -> byte = c0 ^ (ks*32) with
// c0 = ((l5 ^ ((l31>>1)&3)) << 4). Bank audit: group g = (4r+c) mod 8 covers
// all 8 groups per 8 rows -> 8 accesses/group = b128 minimum, 0 conflicts.
// C/D mapping (measured m74/m101): col = lane&31, row = (reg&3)+8*(reg>>2)+4*(lane>>5).
// Race audit / staging / swizzle / XCD mapping: unchanged from R12 (proven).
template <int EPI>
__global__ __launch_bounds__(512)
void gemm_i8_kernel(const int8_t* __restrict__ A,
                    const int8_t* __restrict__ B,
                    const int Nout, const int K,
                    const float* __restrict__ scaleA,   // EPI1: in_scale[row]
                    const float* __restrict__ scaleB,   // w1_scale / w2_scale [col]
                    const float* __restrict__ bias,     // b1 / b2 [col]
                    unsigned* __restrict__ rowmax,      // EPI1: atomic out; EPI2: in
                    __hip_bfloat16* __restrict__ aout,  // EPI1: activations out
                    float* __restrict__ out)            // EPI2: final out
{
    __shared__ int8_t As[3][128 * 64];
    __shared__ int8_t Bs[3][256 * 64];

    const int tid  = threadIdx.x;
    const int lane = tid & 63;
    const int w    = tid >> 6;          // 0..7
    const int wm   = w >> 2;            // 0..1  (M half: 64 rows each)
    const int wn   = w & 3;             // 0..3  (N quarter: 64 cols)
    const int l31  = lane & 31, l5 = lane >> 5;

    // ---- XCD-aware 2D chunk mapping (bijective; gy==32, gx%4==0 here) ----
    const int gx = gridDim.x;
    const int wg  = blockIdx.y * gx + blockIdx.x;
    const int xcd = wg & 7;
    const int idx = wg >> 3;
    const int xr = xcd >> 2, xc = xcd & 3;          // XCDs as 2 x 4
    const int row_t = xr * 16 + (idx & 15);          // column-major in region
    const int col_t = xc * (gx >> 2) + (idx >> 4);
    const int row0 = row_t * 128;
    const int col0 = col_t * 256;

    const int nt = K >> 6;

    // staging: slot s -> row s>>2, chunk (s&3)^((s>>3)&3); one g16 for all slots
    const int srow = tid >> 2;                       // 0..127
    const int g16  = ((tid & 3) ^ ((tid >> 3) & 3)) << 4;

    // 32x32 frag ds_read addressing: row r = base + l31 (base multiple of 32),
    // chunk c = ((ks<<1)|l5) ^ ((l31>>1)&3); byte = c0 ^ (ks*32)
    const int rbA = ((wm << 6) + l31) << 6;          // byte base; + mf*2048
    const int rbB = ((wn << 6) + l31) << 6;          // byte base; + nf*2048
    const int c0  = (l5 ^ ((l31 >> 1) & 3)) << 4;

    i32x16 acc[2][2] = {};

    // persistent staging pointers (advance +64 bytes per staged K-tile)
    const int8_t* psa  = A + (size_t)(row0 + srow) * K + g16;
    const int8_t* psb0 = B + (size_t)(col0 + srow) * K + g16;
    const int8_t* psb1 = B + (size_t)(col0 + 128 + srow) * K + g16;

#define STAGE3(DBUF, PA, PB0, PB1)                                                    \
    {                                                                                 \
        __builtin_amdgcn_global_load_lds((glb_u32*)(PA),                              \
            (lds_u32*)&As[(DBUF)][tid << 4], 16, 0, 0);                               \
        __builtin_amdgcn_global_load_lds((glb_u32*)(PB0),                             \
            (lds_u32*)&Bs[(DBUF)][tid << 4], 16, 0, 0);                               \
        __builtin_amdgcn_global_load_lds((glb_u32*)(PB1),                             \
            (lds_u32*)&Bs[(DBUF)][(tid + 512) << 4], 16, 0, 0);                       \
    }

#define BODY(BUFC, OFF)                                                               \
    {                                                                                 \
        STAGE3((((BUFC) + 2) % 3), psa, psb0, psb1);                                  \
        if (tt + (OFF) < nt - 3) { psa += 64; psb0 += 64; psb1 += 64; }               \
        i32x4 fA[2][2], fB[2][2];                                                     \
        _Pragma("unroll")                                                             \
        for (int mf_ = 0; mf_ < 2; ++mf_)                                             \
            _Pragma("unroll")                                                         \
            for (int ks_ = 0; ks_ < 2; ++ks_)                                         \
                fA[mf_][ks_] = *(const i32x4*)(&As[(BUFC)][rbA + mf_ * 2048 +         \
                                                          (c0 ^ (ks_ * 32))]);        \
        _Pragma("unroll")                                                             \
        for (int nf_ = 0; nf_ < 2; ++nf_)                                             \
            _Pragma("unroll")                                                         \
            for (int ks_ = 0; ks_ < 2; ++ks_)                                         \
                fB[nf_][ks_] = *(const i32x4*)(&Bs[(BUFC)][rbB + nf_ * 2048 +         \
                                                          (c0 ^ (ks_ * 32))]);        \
        __builtin_amdgcn_s_setprio(1);                                                \
        _Pragma("unroll")                                                             \
        for (int ks_ = 0; ks_ < 2; ++ks_)                                             \
            _Pragma("unroll")                                                         \
            for (int mf_ = 0; mf_ < 2; ++mf_)                                         \
                _Pragma("unroll")                                                     \
                for (int nf_ = 0; nf_ < 2; ++nf_)                                     \
                    acc[mf_][nf_] = __builtin_amdgcn_mfma_i32_32x32x32_i8(            \
                        fA[mf_][ks_], fB[nf_][ks_], acc[mf_][nf_], 0, 0, 0);          \
        __builtin_amdgcn_s_setprio(0);                                                \
        asm volatile("s_waitcnt vmcnt(3)" ::: "memory");                              \
        __builtin_amdgcn_s_barrier();                                                 \
    }

    // prologue: stage tiles 0 -> buf0, 1 -> buf1; pointers then at tile 2
    STAGE3(0, psa, psb0, psb1);
    STAGE3(1, psa + 64, psb0 + 64, psb1 + 64);
    psa += 128; psb0 += 128; psb1 += 128;
    asm volatile("s_waitcnt vmcnt(3)" ::: "memory");   // tile 0 complete
    __builtin_amdgcn_s_barrier();

    int tt = 0;
    for (; tt + 3 <= nt; tt += 3) {
        BODY(0, 0);
        BODY(1, 1);
        BODY(2, 2);
    }
    for (; tt < nt; ++tt) {          // remainder (nt%3 bodies; nt in {64,256} -> 1)
        const int rb = tt % 3;
        BODY(rb, 0);
    }
    asm volatile("s_waitcnt vmcnt(0)" ::: "memory");
    __builtin_amdgcn_s_barrier();
#undef BODY
#undef STAGE3

    // C/D mapping for 32x32 (measured): col = lane&31, row = (reg&3)+8*(reg>>2)+4*(lane>>5)
    if (EPI == 1) {
#pragma unroll
        for (int mf = 0; mf < 2; ++mf) {
#pragma unroll
            for (int reg = 0; reg < 16; ++reg) {
                const int grow = row0 + (wm << 6) + mf * 32 +
                                 (reg & 3) + 8 * (reg >> 2) + 4 * l5;
                const float sa = scaleA[grow];
                float vmax = 0.0f;
                float gl[2];
#pragma unroll
                for (int nf = 0; nf < 2; ++nf) {
                    const int gcol = col0 + (wn << 6) + nf * 32 + l31;
                    const float y = (float)acc[mf][nf][reg] * sa * scaleB[gcol] + bias[gcol];
                    gl[nf] = 0.5f * y * (1.0f + erff(y * 0.70710678118654752f));
                    aout[(size_t)grow * DFF + gcol] = __float2bfloat16(gl[nf]);
                    vmax = fmaxf(vmax, fabsf(gl[nf]));
                }
#pragma unroll
                for (int off = 1; off < 32; off <<= 1)
                    vmax = fmaxf(vmax, __shfl_xor(vmax, off));
                if (l31 == 0) atomicMax(&rowmax[grow], __float_as_uint(vmax));
            }
        }
    } else {
#pragma unroll
        for (int mf = 0; mf < 2; ++mf) {
#pragma unroll
            for (int reg = 0; reg < 16; ++reg) {
                const int grow = row0 + (wm << 6) + mf * 32 +
                                 (reg & 3) + 8 * (reg >> 2) + 4 * l5;
                const float s2 = fmaxf(__uint_as_float(rowmax[grow]) * (1.0f / 127.0f), 1e-8f);
#pragma unroll
                for (int nf = 0; nf < 2; ++nf) {
                    const int gcol = col0 + (wn << 6) + nf * 32 + l31;
                    out[(size_t)grow * Nout + gcol] =
                        (float)acc[mf][nf][reg] * s2 * scaleB[gcol] + bias[gcol];
                }
            }
        }
    }
}

// ---------------- dynamic requant: q2 = clip(rint(a / s2), -128, 127) ----------------
__global__ void quant_kernel(const unsigned short* __restrict__ a,  // bf16 bits
                             const unsigned* __restrict__ rowmax,
                             int8_t* __restrict__ q2)
{
    const size_t nvec = (size_t)TOKENS * DFF / 8;
    size_t i = (size_t)blockIdx.x * blockDim.x + threadIdx.x;
    const size_t stride = (size_t)gridDim.x * blockDim.x;
    for (; i < nvec; i += stride) {
        const size_t e0 = i * 8;
        const int n = (int)(e0 >> 14);  // / DFF
        const float s2 = fmaxf(__uint_as_float(rowmax[n]) * (1.0f / 127.0f), 1e-8f);
        const float inv = 1.0f / s2;
        const uint4 v = *(const uint4*)(a + e0);
        const unsigned words[4] = {v.x, v.y, v.z, v.w};
        int qi[8];
#pragma unroll
        for (int j = 0; j < 4; ++j) {
            const float f0 = __uint_as_float((words[j] & 0xffffu) << 16);
            const float f1 = __uint_as_float(words[j] & 0xffff0000u);
            qi[2 * j]     = (int)fminf(fmaxf(rintf(f0 * inv), -128.0f), 127.0f);
            qi[2 * j + 1] = (int)fminf(fmaxf(rintf(f1 * inv), -128.0f), 127.0f);
        }
        const unsigned p0 = (unsigned(qi[0]) & 255u) | ((unsigned(qi[1]) & 255u) << 8) |
                            ((unsigned(qi[2]) & 255u) << 16) | ((unsigned(qi[3]) & 255u) << 24);
        const unsigned p1 = (unsigned(qi[4]) & 255u) | ((unsigned(qi[5]) & 255u) << 8) |
                            ((unsigned(qi[6]) & 255u) << 16) | ((unsigned(qi[7]) & 255u) << 24);
        ((uint2*)q2)[i] = make_uint2(p0, p1);
    }
}

extern "C" void kernel_launch(void* const* d_in, const int* in_sizes, int n_in,
                              void* d_out, int out_size, void* d_ws, size_t ws_size,
                              hipStream_t stream) {
    const int*   q_in     = (const int*)d_in[0];
    const float* in_scale = (const float*)d_in[1];
    const int*   w1_q     = (const int*)d_in[2];
    const float* w1_scale = (const float*)d_in[3];
    const float* b1       = (const float*)d_in[4];
    const int*   w2_q     = (const int*)d_in[5];
    const float* w2_scale = (const float*)d_in[6];
    const float* b2       = (const float*)d_in[7];
    float* out = (float*)d_out;

    // workspace layout (total 336 MiB + 16 KiB)
    char* ws = (char*)d_ws;
    int8_t* A1 = (int8_t*)(ws);                                  //  16 MiB  q_in int8
    int8_t* W1 = (int8_t*)(ws + (size_t)16  * 1048576);          //  64 MiB
    int8_t* W2 = (int8_t*)(ws + (size_t)80  * 1048576);          //  64 MiB
    int8_t* Q2 = (int8_t*)(ws + (size_t)144 * 1048576);          //  64 MiB
    unsigned short* ABUF = (unsigned short*)(ws + (size_t)208 * 1048576);  // 128 MiB bf16 acts
    unsigned* ROWMAX = (unsigned*)(ws + (size_t)336 * 1048576);  //  16 KiB

    zero_u32_kernel<<<dim3(16), dim3(256), 0, stream>>>(ROWMAX, TOKENS);
    pack_i8_kernel<<<dim3(1024), dim3(256), 0, stream>>>(q_in, (unsigned*)A1, (long)TOKENS * DMODEL / 4);
    pack_i8_kernel<<<dim3(4096), dim3(256), 0, stream>>>(w1_q, (unsigned*)W1, (long)DFF * DMODEL / 4);
    pack_i8_kernel<<<dim3(4096), dim3(256), 0, stream>>>(w2_q, (unsigned*)W2, (long)DMODEL * DFF / 4);

    gemm_i8_kernel<1><<<dim3(DFF / 256, TOKENS / 128), dim3(512), 0, stream>>>(
        A1, W1, DFF, DMODEL, in_scale, w1_scale, b1, ROWMAX,
        (__hip_bfloat16*)ABUF, nullptr);

    quant_kernel<<<dim3(4096), dim3(256), 0, stream>>>(ABUF, ROWMAX, Q2);

    gemm_i8_kernel<2><<<dim3(DMODEL / 256, TOKENS / 128), dim3(512), 0, stream>>>(
        Q2, W2, DMODEL, DFF, nullptr, w2_scale, b2, ROWMAX,
        nullptr, out);
}

// Round 14
// 813.835 us; speedup vs baseline: 1.1406x; 1.1406x over previous
//
#include <hip/hip_runtime.h>
#include <hip/hip_bf16.h>
#include <cstdint>
#include <math.h>

#define TOKENS 4096
#define DMODEL 4096
#define DFF    16384

typedef __attribute__((ext_vector_type(4))) int i32x4;
typedef __attribute__((address_space(1))) unsigned int glb_u32;
typedef __attribute__((address_space(3))) unsigned int lds_u32;

// ---------------- pack: int32 -> int8 (values already in [-127,127]) ----------------
__global__ void pack_i8_kernel(const int* __restrict__ src, unsigned* __restrict__ dst, long n4) {
    long i = (long)blockIdx.x * blockDim.x + threadIdx.x;
    const long stride = (long)gridDim.x * blockDim.x;
    for (; i < n4; i += stride) {
        const int4 v = ((const int4*)src)[i];
        unsigned p = (unsigned(v.x) & 255u) | ((unsigned(v.y) & 255u) << 8) |
                     ((unsigned(v.z) & 255u) << 16) | ((unsigned(v.w) & 255u) << 24);
        dst[i] = p;
    }
}

__global__ void zero_u32_kernel(unsigned* __restrict__ p, int n) {
    int i = blockIdx.x * blockDim.x + threadIdx.x;
    if (i < n) p[i] = 0u;
}

// ---------------- int8 GEMM, C[row][col] = sum_k A[row][k]*B[col][k] ----------------
// R14 = R12 (128x256 tile, BK=64, 512 thr / 8 waves 2Mx4N, wave tile 64x64,
// 16x16x64 MFMA [proven zero-conflict frag math], pointer staging, literal-buf
// unrolled loop) with ONE structural change: 3 LDS buffers -> 2 (48KB) so
// THREE blocks co-reside per CU (the only lever that has moved MfmaUtil:
// 1->2 domains = 23->31%). Stage-ahead-1 with end-of-body vmcnt(0); R8 vs R10
// showed drain==counted at equal domain count, and here the drain slack is a
// full body (~1k cyc at 3-way CU sharing) >> L2 latency.
// Loop body t (buf = t&1, literal): STAGE(t+1 -> buf^1) [3 gloads, pointers
// clamped at tile nt-1 -> final body restages nt-1 into the dead buffer,
// benign]; ds_read 8 frags (buf; compiler fine-grained lgkm); 16 MFMA;
// vmcnt(0); s_barrier.
// Race audit: reads of buf complete (lgkm before MFMA) before each wave's
// barrier arrival at body t's end; the stage into buf issued at body t+1 is
// after that barrier -> no overwrite of live reads. vmcnt(0)+barrier at body
// t's end publishes tile t+1 to all waves. No cross-wave timing assumptions.
// LDS swizzle (proven, 0 conflicts): 64B rows, chunk ^= (row>>1)&3; staging
// dest linear, source pre-swizzled g16 (lane-constant, invariant under +256k).
// XCD 2D chunking (proven): 8 XCDs as 2x4, column-major within each XCD's
// 16x(gx/4) region (gy==32, gx%4==0 for both GEMMs).
// fc1 grid 2048 blocks -> 3 domains/CU; fc2 grid 512 -> 2/CU (grid-capped).
template <int EPI>
__global__ __launch_bounds__(512)
void gemm_i8_kernel(const int8_t* __restrict__ A,
                    const int8_t* __restrict__ B,
                    const int Nout, const int K,
                    const float* __restrict__ scaleA,   // EPI1: in_scale[row]
                    const float* __restrict__ scaleB,   // w1_scale / w2_scale [col]
                    const float* __restrict__ bias,     // b1 / b2 [col]
                    unsigned* __restrict__ rowmax,      // EPI1: atomic out; EPI2: in
                    __hip_bfloat16* __restrict__ aout,  // EPI1: activations out
                    float* __restrict__ out)            // EPI2: final out
{
    __shared__ int8_t As[2][128 * 64];
    __shared__ int8_t Bs[2][256 * 64];

    const int tid  = threadIdx.x;
    const int lane = tid & 63;
    const int w    = tid >> 6;          // 0..7
    const int wm   = w >> 2;            // 0..1  (M half: 64 rows each)
    const int wn   = w & 3;             // 0..3  (N quarter: 64 cols)
    const int l15  = lane & 15, l4 = lane >> 4;

    // ---- XCD-aware 2D chunk mapping (bijective; gy==32, gx%4==0 here) ----
    const int gx = gridDim.x;
    const int wg  = blockIdx.y * gx + blockIdx.x;
    const int xcd = wg & 7;
    const int idx = wg >> 3;
    const int xr = xcd >> 2, xc = xcd & 3;          // XCDs as 2 x 4
    const int row_t = xr * 16 + (idx & 15);          // column-major in region
    const int col_t = xc * (gx >> 2) + (idx >> 4);
    const int row0 = row_t * 128;
    const int col0 = col_t * 256;

    const int nt = K >> 6;

    // staging: slot s -> row s>>2, chunk (s&3)^((s>>3)&3); one g16 for all slots
    const int srow = tid >> 2;                       // 0..127
    const int g16  = ((tid & 3) ^ ((tid >> 3) & 3)) << 4;

    // frag ds_read addressing: row r, chunk c = l4 ^ ((r>>1)&3); (r>>1)&3 == (l15>>1)&3
    const int rbA = ((wm << 6) + l15) << 6;          // byte base; + m*1024
    const int rbB = ((wn << 6) + l15) << 6;          // byte base; + n*1024
    const int c0  = (l4 ^ ((l15 >> 1) & 3)) << 4;

    i32x4 acc[4][4] = {};

    // persistent staging pointers (advance +64 bytes per staged K-tile)
    const int8_t* psa  = A + (size_t)(row0 + srow) * K + g16;
    const int8_t* psb0 = B + (size_t)(col0 + srow) * K + g16;
    const int8_t* psb1 = B + (size_t)(col0 + 128 + srow) * K + g16;

#define STAGE3(DBUF, PA, PB0, PB1)                                                    \
    {                                                                                 \
        __builtin_amdgcn_global_load_lds((glb_u32*)(PA),                              \
            (lds_u32*)&As[(DBUF)][tid << 4], 16, 0, 0);                               \
        __builtin_amdgcn_global_load_lds((glb_u32*)(PB0),                             \
            (lds_u32*)&Bs[(DBUF)][tid << 4], 16, 0, 0);                               \
        __builtin_amdgcn_global_load_lds((glb_u32*)(PB1),                             \
            (lds_u32*)&Bs[(DBUF)][(tid + 512) << 4], 16, 0, 0);                       \
    }

#define BODY(BUFC, OFF)                                                               \
    {                                                                                 \
        STAGE3((BUFC) ^ 1, psa, psb0, psb1);   /* tile t+1 (clamped at nt-1) */       \
        if (tt + (OFF) < nt - 2) { psa += 64; psb0 += 64; psb1 += 64; }               \
        i32x4 fA[4], fB[4];                                                           \
        _Pragma("unroll")                                                             \
        for (int m_ = 0; m_ < 4; ++m_)                                                \
            fA[m_] = *(const i32x4*)(&As[(BUFC)][rbA + m_ * 1024 + c0]);              \
        _Pragma("unroll")                                                             \
        for (int n_ = 0; n_ < 4; ++n_)                                                \
            fB[n_] = *(const i32x4*)(&Bs[(BUFC)][rbB + n_ * 1024 + c0]);              \
        __builtin_amdgcn_s_setprio(1);                                                \
        _Pragma("unroll")                                                             \
        for (int m_ = 0; m_ < 4; ++m_)                                                \
            _Pragma("unroll")                                                         \
            for (int n_ = 0; n_ < 4; ++n_)                                            \
                acc[m_][n_] = __builtin_amdgcn_mfma_i32_16x16x64_i8(                  \
                    fA[m_], fB[n_], acc[m_][n_], 0, 0, 0);                            \
        __builtin_amdgcn_s_setprio(0);                                                \
        asm volatile("s_waitcnt vmcnt(0)" ::: "memory");                              \
        __builtin_amdgcn_s_barrier();                                                 \
    }

    // prologue: stage tile 0 -> buf0; pointers then at tile 1
    STAGE3(0, psa, psb0, psb1);
    psa += 64; psb0 += 64; psb1 += 64;
    asm volatile("s_waitcnt vmcnt(0)" ::: "memory");
    __builtin_amdgcn_s_barrier();

    int tt = 0;
    for (; tt < nt; tt += 2) {       // nt even (64 or 256)
        BODY(0, 0);
        BODY(1, 1);
    }
#undef BODY
#undef STAGE3

    // C/D frag mapping (gfx950, dtype-independent): col = lane&15, row = (lane>>4)*4 + reg
    if (EPI == 1) {
#pragma unroll
        for (int m = 0; m < 4; ++m) {
#pragma unroll
            for (int reg = 0; reg < 4; ++reg) {
                const int grow = row0 + (wm << 6) + m * 16 + l4 * 4 + reg;
                const float sa = scaleA[grow];
                float vmax = 0.0f;
#pragma unroll
                for (int n = 0; n < 4; ++n) {
                    const int gcol = col0 + (wn << 6) + n * 16 + l15;
                    const float y = (float)acc[m][n][reg] * sa * scaleB[gcol] + bias[gcol];
                    const float gl = 0.5f * y * (1.0f + erff(y * 0.70710678118654752f));
                    aout[(size_t)grow * DFF + gcol] = __float2bfloat16(gl);
                    vmax = fmaxf(vmax, fabsf(gl));
                }
#pragma unroll
                for (int off = 1; off < 16; off <<= 1)
                    vmax = fmaxf(vmax, __shfl_xor(vmax, off));
                if (l15 == 0) atomicMax(&rowmax[grow], __float_as_uint(vmax));
            }
        }
    } else {
#pragma unroll
        for (int m = 0; m < 4; ++m) {
#pragma unroll
            for (int reg = 0; reg < 4; ++reg) {
                const int grow = row0 + (wm << 6) + m * 16 + l4 * 4 + reg;
                const float s2 = fmaxf(__uint_as_float(rowmax[grow]) * (1.0f / 127.0f), 1e-8f);
#pragma unroll
                for (int n = 0; n < 4; ++n) {
                    const int gcol = col0 + (wn << 6) + n * 16 + l15;
                    out[(size_t)grow * Nout + gcol] =
                        (float)acc[m][n][reg] * s2 * scaleB[gcol] + bias[gcol];
                }
            }
        }
    }
}

// ---------------- dynamic requant: q2 = clip(rint(a / s2), -128, 127) ----------------
__global__ void quant_kernel(const unsigned short* __restrict__ a,  // bf16 bits
                             const unsigned* __restrict__ rowmax,
                             int8_t* __restrict__ q2)
{
    const size_t nvec = (size_t)TOKENS * DFF / 8;
    size_t i = (size_t)blockIdx.x * blockDim.x + threadIdx.x;
    const size_t stride = (size_t)gridDim.x * blockDim.x;
    for (; i < nvec; i += stride) {
        const size_t e0 = i * 8;
        const int n = (int)(e0 >> 14);  // / DFF
        const float s2 = fmaxf(__uint_as_float(rowmax[n]) * (1.0f / 127.0f), 1e-8f);
        const float inv = 1.0f / s2;
        const uint4 v = *(const uint4*)(a + e0);
        const unsigned words[4] = {v.x, v.y, v.z, v.w};
        int qi[8];
#pragma unroll
        for (int j = 0; j < 4; ++j) {
            const float f0 = __uint_as_float((words[j] & 0xffffu) << 16);
            const float f1 = __uint_as_float(words[j] & 0xffff0000u);
            qi[2 * j]     = (int)fminf(fmaxf(rintf(f0 * inv), -128.0f), 127.0f);
            qi[2 * j + 1] = (int)fminf(fmaxf(rintf(f1 * inv), -128.0f), 127.0f);
        }
        const unsigned p0 = (unsigned(qi[0]) & 255u) | ((unsigned(qi[1]) & 255u) << 8) |
                            ((unsigned(qi[2]) & 255u) << 16) | ((unsigned(qi[3]) & 255u) << 24);
        const unsigned p1 = (unsigned(qi[4]) & 255u) | ((unsigned(qi[5]) & 255u) << 8) |
                            ((unsigned(qi[6]) & 255u) << 16) | ((unsigned(qi[7]) & 255u) << 24);
        ((uint2*)q2)[i] = make_uint2(p0, p1);
    }
}

extern "C" void kernel_launch(void* const* d_in, const int* in_sizes, int n_in,
                              void* d_out, int out_size, void* d_ws, size_t ws_size,
                              hipStream_t stream) {
    const int*   q_in     = (const int*)d_in[0];
    const float* in_scale = (const float*)d_in[1];
    const int*   w1_q     = (const int*)d_in[2];
    const float* w1_scale = (const float*)d_in[3];
    const float* b1       = (const float*)d_in[4];
    const int*   w2_q     = (const int*)d_in[5];
    const float* w2_scale = (const float*)d_in[6];
    const float* b2       = (const float*)d_in[7];
    float* out = (float*)d_out;

    // workspace layout (total 336 MiB + 16 KiB)
    char* ws = (char*)d_ws;
    int8_t* A1 = (int8_t*)(ws);                                  //  16 MiB  q_in int8
    int8_t* W1 = (int8_t*)(ws + (size_t)16  * 1048576);          //  64 MiB
    int8_t* W2 = (int8_t*)(ws + (size_t)80  * 1048576);          //  64 MiB
    int8_t* Q2 = (int8_t*)(ws + (size_t)144 * 1048576);          //  64 MiB
    unsigned short* ABUF = (unsigned short*)(ws + (size_t)208 * 1048576);  // 128 MiB bf16 acts
    unsigned* ROWMAX = (unsigned*)(ws + (size_t)336 * 1048576);  //  16 KiB

    zero_u32_kernel<<<dim3(16), dim3(256), 0, stream>>>(ROWMAX, TOKENS);
    pack_i8_kernel<<<dim3(1024), dim3(256), 0, stream>>>(q_in, (unsigned*)A1, (long)TOKENS * DMODEL / 4);
    pack_i8_kernel<<<dim3(4096), dim3(256), 0, stream>>>(w1_q, (unsigned*)W1, (long)DFF * DMODEL / 4);
    pack_i8_kernel<<<dim3(4096), dim3(256), 0, stream>>>(w2_q, (unsigned*)W2, (long)DMODEL * DFF / 4);

    gemm_i8_kernel<1><<<dim3(DFF / 256, TOKENS / 128), dim3(512), 0, stream>>>(
        A1, W1, DFF, DMODEL, in_scale, w1_scale, b1, ROWMAX,
        (__hip_bfloat16*)ABUF, nullptr);

    quant_kernel<<<dim3(4096), dim3(256), 0, stream>>>(ABUF, ROWMAX, Q2);

    gemm_i8_kernel<2><<<dim3(DMODEL / 256, TOKENS / 128), dim3(512), 0, stream>>>(
        Q2, W2, DMODEL, DFF, nullptr, w2_scale, b2, ROWMAX,
        nullptr, out);
}